// Round 12
// baseline (608.860 us; speedup 1.0000x reference)
//
#include <hip/hip_runtime.h>

#define N_NODES 50000
#define N_EDGES 800000
#define FEAT    16
#define HID     128
#define NLAYERS 4
#define OUTD    12
#define NGRAPH  1024
#define SCAN_NB 196   // ceil((N_NODES+1)/256)

__device__ inline float4 f4zero() { return make_float4(0.f, 0.f, 0.f, 0.f); }
__device__ inline float4 f4fma(float a, float4 w, float4 acc) {
    acc.x = fmaf(a, w.x, acc.x);
    acc.y = fmaf(a, w.y, acc.y);
    acc.z = fmaf(a, w.z, acc.z);
    acc.w = fmaf(a, w.w, acc.w);
    return acc;
}
__device__ inline float4 f4add(float4 a, float4 b) {
    return make_float4(a.x + b.x, a.y + b.y, a.z + b.z, a.w + b.w);
}
__device__ inline float4 f4relu(float4 a) {
    return make_float4(fmaxf(a.x, 0.f), fmaxf(a.y, 0.f), fmaxf(a.z, 0.f), fmaxf(a.w, 0.f));
}

// ---------------- degree ----------------
__global__ void k_deg(const int* __restrict__ ei, int* __restrict__ degi) {
    int e = blockIdx.x * 256 + threadIdx.x;
    if (e < N_EDGES) atomicAdd(&degi[ei[N_EDGES + e]], 1);
}

// ---------------- scan part (fused: also computes dinv) ----------------
__global__ void k_scan_part(const int* __restrict__ degi, int* __restrict__ part,
                            float* __restrict__ dinv) {
    __shared__ int s[256];
    int t = threadIdx.x;
    int i = blockIdx.x * 256 + t;
    int v = (i < N_NODES) ? degi[i] : 0;
    if (i < N_NODES) dinv[i] = rsqrtf((float)v + 1.0f);
    s[t] = v;
    __syncthreads();
    for (int st = 128; st > 0; st >>= 1) {
        if (t < st) s[t] += s[t + st];
        __syncthreads();
    }
    if (t == 0) part[blockIdx.x] = s[0];
}

__global__ void k_scan_mid(int* __restrict__ part) {
    __shared__ int s[256];
    int t = threadIdx.x;
    int v = (t < SCAN_NB) ? part[t] : 0;
    s[t] = v;
    __syncthreads();
    for (int st = 1; st < 256; st <<= 1) {
        int u = (t >= st) ? s[t - st] : 0;
        __syncthreads();
        s[t] += u;
        __syncthreads();
    }
    if (t < SCAN_NB) part[t] = s[t] - v;   // exclusive
}

__global__ void k_scan_final(const int* __restrict__ degi, const int* __restrict__ part,
                             int* __restrict__ offs) {
    __shared__ int s[256];
    int t = threadIdx.x;
    int i = blockIdx.x * 256 + t;
    int v = (i < N_NODES) ? degi[i] : 0;
    s[t] = v;
    __syncthreads();
    for (int st = 1; st < 256; st <<= 1) {
        int u = (t >= st) ? s[t - st] : 0;
        __syncthreads();
        s[t] += u;
        __syncthreads();
    }
    if (i <= N_NODES) offs[i] = s[t] - v + part[blockIdx.x];
}

// ---------------- CSR fill: packed record {src, dinv[src]} ----------------
__global__ void k_fill(const int* __restrict__ ei, const int* __restrict__ offs,
                       const float* __restrict__ dinv,
                       int* __restrict__ cursor, int2* __restrict__ erec) {
    int e = blockIdx.x * 256 + threadIdx.x;
    if (e < N_EDGES) {
        int srcv = ei[e];
        int dstv = ei[N_EDGES + e];
        int p = atomicAdd(&cursor[dstv], 1);
        erec[offs[dstv] + p] = make_int2(srcv, __float_as_int(dinv[srcv]));
    }
}

// ---------------- fused node-embed MLP: hA = relu(x@We1+be1)@We2+be2 ----------------
#define GM 64
__global__ void __launch_bounds__(256) k_embed_fused(
        const float* __restrict__ x,
        const float* __restrict__ W1, const float* __restrict__ b1,
        const float* __restrict__ W2, const float* __restrict__ b2,
        float* __restrict__ outp) {
    __shared__ float x_l[GM][FEAT];
    __shared__ float a_l[GM][HID];
    int t = threadIdx.x;
    long n0 = (long)blockIdx.x * GM;
    {
        int r  = t >> 2;
        int c4 = (t & 3) << 2;
        long n = n0 + r;
        float4 v = (n < N_NODES) ? *(const float4*)&x[n * FEAT + c4] : f4zero();
        *(float4*)&x_l[r][c4] = v;
    }
    __syncthreads();
    int fgrp = t & 31, ngrp = t >> 5;
    int f4 = fgrp << 2;
    // stage 1: t = relu(x@W1+b1), K=16
    {
        float4 acc[8];
#pragma unroll
        for (int r = 0; r < 8; ++r) acc[r] = f4zero();
#pragma unroll
        for (int k4 = 0; k4 < 4; ++k4) {
            float4 wv[4];
#pragma unroll
            for (int kk = 0; kk < 4; ++kk)
                wv[kk] = *(const float4*)&W1[(k4 * 4 + kk) * HID + f4];
            float4 xv[8];
#pragma unroll
            for (int r = 0; r < 8; ++r)
                xv[r] = *(const float4*)&x_l[ngrp * 8 + r][k4 << 2];
#pragma unroll
            for (int r = 0; r < 8; ++r) {
                acc[r] = f4fma(xv[r].x, wv[0], acc[r]);
                acc[r] = f4fma(xv[r].y, wv[1], acc[r]);
                acc[r] = f4fma(xv[r].z, wv[2], acc[r]);
                acc[r] = f4fma(xv[r].w, wv[3], acc[r]);
            }
        }
        float4 bv = *(const float4*)&b1[f4];
#pragma unroll
        for (int r = 0; r < 8; ++r)
            *(float4*)&a_l[ngrp * 8 + r][f4] = f4relu(f4add(acc[r], bv));
    }
    __syncthreads();
    // stage 2: out = t @ W2 + b2, K=128
    float4 acc[8];
#pragma unroll
    for (int r = 0; r < 8; ++r) acc[r] = f4zero();
#pragma unroll 4
    for (int k4 = 0; k4 < 32; ++k4) {
        float4 wv[4];
#pragma unroll
        for (int kk = 0; kk < 4; ++kk)
            wv[kk] = *(const float4*)&W2[(k4 * 4 + kk) * HID + f4];
        float4 av[8];
#pragma unroll
        for (int r = 0; r < 8; ++r)
            av[r] = *(const float4*)&a_l[ngrp * 8 + r][k4 << 2];
#pragma unroll
        for (int r = 0; r < 8; ++r) {
            acc[r] = f4fma(av[r].x, wv[0], acc[r]);
            acc[r] = f4fma(av[r].y, wv[1], acc[r]);
            acc[r] = f4fma(av[r].z, wv[2], acc[r]);
            acc[r] = f4fma(av[r].w, wv[3], acc[r]);
        }
    }
    float4 bv = *(const float4*)&b2[f4];
#pragma unroll
    for (int r = 0; r < 8; ++r) {
        long n = n0 + ngrp * 8 + r;
        if (n < N_NODES) *(float4*)&outp[n * HID + f4] = f4add(acc[r], bv);
    }
}

// ---------------- dense GEMM: B = A @ W, row-major out ----------------
__global__ void __launch_bounds__(256) k_gemm(
        const float* __restrict__ A, const float* __restrict__ W,
        float* __restrict__ B) {
    __shared__ float a_l[GM][HID];
    int t = threadIdx.x;
    long n0 = (long)blockIdx.x * GM;
#pragma unroll
    for (int i = 0; i < 8; ++i) {
        int p  = t + 256 * i;
        int r  = p >> 5;
        int c4 = (p & 31) << 2;
        long n = n0 + r;
        float4 v = (n < N_NODES) ? *(const float4*)&A[n * HID + c4] : f4zero();
        *(float4*)&a_l[r][c4] = v;
    }
    __syncthreads();
    int fgrp = t & 31, ngrp = t >> 5;
    int f4 = fgrp << 2;
    float4 acc[8];
#pragma unroll
    for (int r = 0; r < 8; ++r) acc[r] = f4zero();
#pragma unroll 4
    for (int k4 = 0; k4 < 32; ++k4) {
        float4 wv[4];
#pragma unroll
        for (int kk = 0; kk < 4; ++kk)
            wv[kk] = *(const float4*)&W[(k4 * 4 + kk) * HID + f4];
        float4 av[8];
#pragma unroll
        for (int r = 0; r < 8; ++r)
            av[r] = *(const float4*)&a_l[ngrp * 8 + r][k4 << 2];
#pragma unroll
        for (int r = 0; r < 8; ++r) {
            acc[r] = f4fma(av[r].x, wv[0], acc[r]);
            acc[r] = f4fma(av[r].y, wv[1], acc[r]);
            acc[r] = f4fma(av[r].z, wv[2], acc[r]);
            acc[r] = f4fma(av[r].w, wv[3], acc[r]);
        }
    }
#pragma unroll
    for (int r = 0; r < 8; ++r) {
        long n = n0 + ngrp * 8 + r;
        if (n < N_NODES) *(float4*)&B[n * HID + f4] = acc[r];
    }
}

// ---------------- CSR aggregation + self-loop + bias + relu ----------------
// TWO dsts per wave: half-wave (32 lanes x float4 = 512B) owns one row.
// Each gather instruction fetches 2 rows (1KB); per-edge shfl/FMA halves.
// erec staged 32/chunk per half; shfl broadcasts stay within the half.
__global__ void __launch_bounds__(256) k_agg(
        const float* __restrict__ hp,
        const int2* __restrict__ erec, const int* __restrict__ offs,
        const float* __restrict__ dinv, const float* __restrict__ bias,
        float* __restrict__ hout) {
    int t = threadIdx.x;
    int lane = t & 63;
    int w = t >> 6;
    int half = lane >> 5, l32 = lane & 31;
    long i = (long)blockIdx.x * 8 + w * 2 + half;
    if ((long)blockIdx.x * 8 + w * 2 >= N_NODES) return;   // wave-uniform
    bool valid = i < N_NODES;
    float di = valid ? dinv[i] : 0.f;
    int s0 = valid ? offs[i] : 0;
    int s1 = valid ? offs[i + 1] : 0;
    const float4* hp4 = (const float4*)hp;
    float4 bv = ((const float4*)bias)[l32];
    float4 acc = f4zero();
    if (valid) {
        float4 self = hp4[i * 32 + l32];
        acc = f4fma(di * di, self, bv);
    }
    int hbase = half << 5;                      // shfl lane base for this half
    for (int base = s0; base < s1; base += 32) {
        int cn = s1 - base; if (cn > 32) cn = 32;
        int last = cn - 1;
        int2 e = (l32 < cn) ? erec[base + l32] : make_int2(0, 0);
        int   sv_l = e.x;
        float nm_l = __int_as_float(e.y);
        for (int k = 0; k < cn; k += 8) {
            int a[8]; float m[8];
#pragma unroll
            for (int u = 0; u < 8; ++u) {
                int kk = k + u;
                int ks = kk < last ? kk : last;       // clamp to last real edge
                a[u] = __shfl(sv_l, hbase | ks);
                float mu = __shfl(nm_l, hbase | ks);
                m[u] = (kk < cn) ? mu * di : 0.f;
            }
            float4 v[8];
#pragma unroll
            for (int u = 0; u < 8; ++u) v[u] = hp4[(long)a[u] * 32 + l32];
#pragma unroll
            for (int u = 0; u < 8; ++u) acc = f4fma(m[u], v[u], acc);
        }
    }
    if (valid) ((float4*)hout)[i * 32 + l32] = f4relu(acc);
}

// ---------------- fused pooling + output head: one block per graph ----------------
// batch_idx is sorted; binary-search the node range, mean-pool, then @Wo + bo.
__global__ void __launch_bounds__(HID) k_poolout(
        const float* __restrict__ h, const int* __restrict__ batch,
        const float* __restrict__ Wo, const float* __restrict__ bo,
        float* __restrict__ out) {
    __shared__ float p[HID];
    __shared__ int range[2];
    int g = blockIdx.x;
    int f = threadIdx.x;
    if (f < 2) {
        int key = g + f;            // lower_bound(batch, key)
        int lo = 0, hi = N_NODES;
        while (lo < hi) {
            int mid = (lo + hi) >> 1;
            if (batch[mid] < key) lo = mid + 1; else hi = mid;
        }
        range[f] = lo;
    }
    __syncthreads();
    int n0 = range[0], n1 = range[1];
    float acc = 0.f;
    for (int n = n0; n < n1; ++n) acc += h[(long)n * HID + f];
    float inv = 1.0f / fmaxf((float)(n1 - n0), 1.0f);
    p[f] = acc * inv;
    __syncthreads();
    if (f < OUTD) {
        float o = bo[f];
#pragma unroll 8
        for (int k = 0; k < HID; ++k) o = fmaf(p[k], Wo[k * OUTD + f], o);
        out[g * OUTD + f] = o;
    }
}

extern "C" void kernel_launch(void* const* d_in, const int* in_sizes, int n_in,
                              void* d_out, int out_size, void* d_ws, size_t ws_size,
                              hipStream_t stream) {
    const float* x    = (const float*)d_in[0];
    const int*   ei   = (const int*)d_in[1];
    // d_in[2] edge_attr unused
    const int*   bidx = (const int*)d_in[3];
    const float* We1  = (const float*)d_in[4];
    const float* be1  = (const float*)d_in[5];
    const float* We2  = (const float*)d_in[6];
    const float* be2  = (const float*)d_in[7];
    const float* Wg   = (const float*)d_in[8];
    const float* bg   = (const float*)d_in[9];
    const float* Wo   = (const float*)d_in[10];
    const float* bo   = (const float*)d_in[11];
    float* out = (float*)d_out;

    // ---- workspace layout (256B aligned) ----
    char* ws = (char*)d_ws;
    size_t o = 0;
    auto take = [&](size_t bytes) { size_t r = o; o += (bytes + 255) & ~(size_t)255; return r; };
    size_t off_degi   = take((size_t)N_NODES * 4);
    size_t off_cursor = take((size_t)N_NODES * 4);
    size_t zero_bytes = o;                       // [0, o) gets memset to 0
    size_t off_dinv   = take((size_t)N_NODES * 4);
    size_t off_offs   = take((size_t)(N_NODES + 1) * 4);
    size_t off_part   = take((size_t)256 * 4);
    size_t off_erec   = take((size_t)N_EDGES * 8);
    size_t off_hA     = take((size_t)N_NODES * HID * 4);
    size_t off_hB     = take((size_t)N_NODES * HID * 4);

    int*   degi   = (int*)(ws + off_degi);
    int*   cursor = (int*)(ws + off_cursor);
    float* dinv   = (float*)(ws + off_dinv);
    int*   offs   = (int*)(ws + off_offs);
    int*   part   = (int*)(ws + off_part);
    int2*  erec   = (int2*)(ws + off_erec);
    float* hA     = (float*)(ws + off_hA);
    float* hB     = (float*)(ws + off_hB);

    hipMemsetAsync(d_ws, 0, zero_bytes, stream);

    // degree + dinv + CSR build (amortized across 4 layers)
    k_deg<<<(N_EDGES + 255) / 256, 256, 0, stream>>>(ei, degi);
    k_scan_part<<<SCAN_NB, 256, 0, stream>>>(degi, part, dinv);
    k_scan_mid<<<1, 256, 0, stream>>>(part);
    k_scan_final<<<SCAN_NB, 256, 0, stream>>>(degi, part, offs);
    k_fill<<<(N_EDGES + 255) / 256, 256, 0, stream>>>(ei, offs, dinv, cursor, erec);

    // fused node-embed MLP -> hA
    int tile_grid = (N_NODES + GM - 1) / GM;
    k_embed_fused<<<tile_grid, 256, 0, stream>>>(x, We1, be1, We2, be2, hA);

    // 4 GCN layers: hB = hA @ Wg[l]; hA = relu(agg(hB) + self + bias)
    for (int l = 0; l < NLAYERS; ++l) {
        k_gemm<<<tile_grid, 256, 0, stream>>>(hA, Wg + (size_t)l * HID * HID, hB);
        k_agg<<<(N_NODES + 7) / 8, 256, 0, stream>>>(hB, erec, offs, dinv,
                                                     bg + (size_t)l * HID, hA);
    }

    // fused pooling + output head
    k_poolout<<<NGRAPH, HID, 0, stream>>>(hA, bidx, Wo, bo, out);
}